// Round 24
// baseline (81.044 us; speedup 1.0000x reference)
//
#include <hip/hip_runtime.h>

typedef unsigned short u16;
typedef __attribute__((ext_vector_type(4))) float f32x4;
typedef __attribute__((ext_vector_type(8))) short bf16x8;
typedef __attribute__((ext_vector_type(4))) int i32x4;
typedef __attribute__((ext_vector_type(4))) unsigned short u16x4;

#define MFMA_16x16x32(a, b, c) __builtin_amdgcn_mfma_f32_16x16x32_bf16((a), (b), (c), 0, 0, 0)

typedef __attribute__((address_space(1))) const unsigned int gas_u32;
typedef __attribute__((address_space(3))) unsigned int las_u32;
__device__ __forceinline__ void gload16(const void* g, void* l) {
    __builtin_amdgcn_global_load_lds((gas_u32*)g, (las_u32*)l, 16, 0, 0);
}

__device__ __forceinline__ u16 f2bf(float f) {
    unsigned u = __float_as_uint(f);
    u += 0x7fffu + ((u >> 16) & 1u);
    return (u16)(u >> 16);
}

__device__ __forceinline__ unsigned cvt_pk_bf16(float lo, float hi) {
    unsigned r;
    asm("v_cvt_pk_bf16_f32 %0, %1, %2" : "=v"(r) : "v"(lo), "v"(hi));
    return r;
}

// ---------------- fused pack: x->bf16 | Wqkv permuted+transposed | Wo transposed --------
__global__ void pack_all_kernel(const float* __restrict__ x, u16* __restrict__ xb,
                                const float* __restrict__ Wq, const float* __restrict__ Wk,
                                const float* __restrict__ Wv, u16* __restrict__ Wqkv_t,
                                const float* __restrict__ Wo, u16* __restrict__ Wot) {
    __shared__ u16 tile[64][65];
    int b = blockIdx.x;
    if (b < 4096) {
        int i = b * 256 + threadIdx.x;
        f32x4 v = ((const f32x4*)x)[i];
        u16x4 o;
        o.x = f2bf(v.x); o.y = f2bf(v.y); o.z = f2bf(v.z); o.w = f2bf(v.w);
        ((u16x4*)xb)[i] = o;
        return;
    }
    int tx = threadIdx.x & 63, tq = threadIdx.x >> 6;
    if (b < 4480) {
        int bb = b - 4096;
        int c0 = (bb & 15) * 64;   // K dim (0..1023)
        int j0 = (bb >> 4) * 64;   // N dim (0..1535)
        int tgt = j0 >> 9;
        int jj0 = j0 & 511;
        const float* W = (tgt == 0) ? Wq : (tgt == 1) ? Wk : Wv;
#pragma unroll
        for (int p = 0; p < 16; ++p) {
            int cl = p * 4 + tq;
            int c = c0 + cl;
            int srcRow = 2 * (c & 511) + (c >> 9);
            tile[cl][tx] = f2bf(W[(size_t)srcRow * 512 + jj0 + tx]);
        }
        __syncthreads();
#pragma unroll
        for (int p = 0; p < 16; ++p) {
            int jl = p * 4 + tq;
            Wqkv_t[(size_t)(j0 + jl) * 1024 + c0 + tx] = tile[tx][jl];
        }
    } else {
        int bb = b - 4480;
        int k0 = (bb & 7) * 64;
        int j0 = (bb >> 3) * 64;
#pragma unroll
        for (int p = 0; p < 16; ++p) {
            int kl = p * 4 + tq;
            tile[kl][tx] = f2bf(Wo[(size_t)(k0 + kl) * 512 + j0 + tx]);
        }
        __syncthreads();
#pragma unroll
        for (int p = 0; p < 16; ++p) {
            int jl = p * 4 + tq;
            Wot[(size_t)(j0 + jl) * 512 + k0 + tx] = tile[tx][jl];
        }
    }
}

// ---------------- GEMM: C[M][N] = A[M][K](bf16) @ Bt[N][K](bf16)^T + bias ----------------
// m97-structure, BM=64 grid-uniform (3 blocks/CU for QKV). EPI 1: Q PRE-SCALED by
// 512^-0.5*log2(e); V output TILE-BLOCKED [head][tile][dd][perm(k)].
// Epilogue: bias/indices hoisted; V-fragment r-values consecutive -> u16x4 store.
template <int EPI, int BM>
__global__ __launch_bounds__(256, 2) void gemm_kernel(
    const u16* __restrict__ A, const u16* __restrict__ Bt, int M, int N, int K,
    const float* __restrict__ b0, const float* __restrict__ b1, const float* __restrict__ b2,
    float* __restrict__ outF, u16* __restrict__ outQKV) {
    constexpr int IFR = BM / 32;
    __shared__ __align__(16) char lds[BM * 128 + 16384];
    char* ldsA = lds;
    char* ldsB = lds + BM * 128;
    int t = threadIdx.x;
    int bm = blockIdx.x * BM, bn = blockIdx.y * 128;
    int w = t >> 6, lane = t & 63, g = lane >> 4, q = lane & 15;
    int wr = (w >> 1) * (BM / 2), wc = (w & 1) * 64;
    f32x4 acc[IFR][4] = {};

    int srow = t >> 3;
    int schunk = ((t & 7) ^ (srow & 7)) << 4;
    size_t src_off = (size_t)srow * (size_t)(K * 2) + schunk;
    size_t prow_stride = (size_t)32 * K * 2;
    char* ldsAd = ldsA + t * 16;
    char* ldsBd = ldsB + t * 16;
    const char* Abase = (const char*)A + (size_t)bm * K * 2;
    const char* Bbase = (const char*)Bt + (size_t)bn * K * 2;

    for (int k0 = 0; k0 < K; k0 += 64) {
        __syncthreads();
        const char* Ab = Abase + (size_t)k0 * 2 + src_off;
        const char* Bb = Bbase + (size_t)k0 * 2 + src_off;
#pragma unroll
        for (int p = 0; p < BM / 32; ++p)
            gload16(Ab + p * prow_stride, ldsAd + p * 4096);
#pragma unroll
        for (int p = 0; p < 4; ++p)
            gload16(Bb + p * prow_stride, ldsBd + p * 4096);
        __syncthreads();
#pragma unroll
        for (int ks = 0; ks < 2; ++ks) {
            bf16x8 af[IFR], bfr[4];
#pragma unroll
            for (int i = 0; i < IFR; ++i) {
                int row = wr + i * 16 + q;
                af[i] = *(const bf16x8*)(ldsA + row * 128 + (((ks * 4 + g) ^ (row & 7)) << 4));
            }
#pragma unroll
            for (int j = 0; j < 4; ++j) {
                int col = wc + j * 16 + q;
                bfr[j] = *(const bf16x8*)(ldsB + col * 128 + (((ks * 4 + g) ^ (col & 7)) << 4));
            }
#pragma unroll
            for (int i = 0; i < IFR; ++i)
#pragma unroll
                for (int j = 0; j < 4; ++j)
                    acc[i][j] = MFMA_16x16x32(af[i], bfr[j], acc[i][j]);
        }
    }

#pragma unroll
    for (int i = 0; i < IFR; ++i) {
#pragma unroll
        for (int j = 0; j < 4; ++j) {
            int col = bn + wc + j * 16 + q;
            if (EPI == 0) {
                float bias = b0[col];
#pragma unroll
                for (int r = 0; r < 4; ++r) {
                    int m = bm + wr + i * 16 + g * 4 + r;
                    outF[(size_t)m * N + col] = acc[i][j][r] + bias;
                }
            } else {
                int tt = col >> 9, jj = col & 511;
                const float* bb = (tt == 0) ? b0 : (tt == 1) ? b1 : b2;
                float bias = bb[jj];
                int h = jj >> 6, dd = jj & 63;
                int m0 = bm + wr + i * 16 + g * 4;     // 4-aligned; r-range stays in-tile
                int nb = m0 >> 11, lseq0 = m0 & 2047;
                if (tt == 2) {
                    // t6p for r=0 has low 2 bits 0; dst(r) = dst(0) + r (consecutive u16)
                    int t6 = lseq0 & 63;
                    int t6p = (t6 & 0x20) | ((t6 & 0xC) << 1) | ((t6 & 0x10) >> 2);
                    size_t dst = (size_t)2 * 2097152 +
                                 (size_t)(nb * 8 + h) * 131072 +
                                 (size_t)(lseq0 >> 6) * 4096 + (size_t)dd * 64 + t6p;
                    union { unsigned u2[2]; u16x4 v4; } pk;
                    pk.u2[0] = cvt_pk_bf16(acc[i][j][0] + bias, acc[i][j][1] + bias);
                    pk.u2[1] = cvt_pk_bf16(acc[i][j][2] + bias, acc[i][j][3] + bias);
                    *(u16x4*)(outQKV + dst) = pk.v4;   // 8B-aligned
                } else {
                    float scale = (tt == 0) ? 0.06375872186536607f : 1.0f;
                    size_t base = (size_t)tt * 2097152 +
                                  ((size_t)((nb * 8 + h) * 2048 + lseq0)) * 64 + dd;
#pragma unroll
                    for (int r = 0; r < 4; ++r)
                        outQKV[base + (size_t)r * 64] = f2bf((acc[i][j][r] + bias) * scale);
                }
            }
        }
    }
}

// ------------- flash attention: in-block split-K halves; K LDS-staged, V GLOBAL-direct --
// CU-pair balanced mapping (bids b, b+256 share a CU; qb = {31-m, m}).
// V is tile-blocked (8KB contiguous/tile) and fragment addresses depend only on
// (lane, t) -> identical across the half's 4 waves: L1-resident, broadcast hits.
// (R15's global-V failed on the OLD strided layout: 64 lanes x 4KB-stride gather.)
// Cuts ds_read_b128 16->8 per tile, staging gloads halved, LDS 64->32 KB.
// NO-MAX softmax (Q pre-scaled); raw v_exp_f32; deferred l-reduction.
__global__ __launch_bounds__(512, 4) void attn_kernel(
    const u16* __restrict__ Qb, const u16* __restrict__ Kb, const u16* __restrict__ Vt,
    u16* __restrict__ Ob) {
    __shared__ __align__(16) char lds[32768];  // K[2buf][2half][8KB]; merge overlays
    int bid = blockIdx.x;
    int hi = bid >> 8;                 // 0 or 1
    int u = bid & 255;
    int nh = u & 15;
    int m = u >> 4;                    // [0,16)
    int qb = hi ? m : 31 - m;          // CU-pair (b, b+256): {31-m, m}
    int tid = threadIdx.x;
    int w = tid >> 6, lane = tid & 63;
    int g = lane >> 4, q = lane & 15;
    int half = w >> 2, ws = w & 3;
    int qt = qb * 4 + ws;
    int q_abs = qt * 16 + q;
    int nkt = qb + 1;
    int h0 = (nkt + 1) >> 1;

    const u16* Qp = Qb + (size_t)nh * 131072;
    const char* Kp = (const char*)(Kb + (size_t)nh * 131072);
    const char* Vp = (const char*)(Vt + (size_t)nh * 131072);

    int srow = tid >> 3;
    int schunk = ((tid & 7) ^ (srow & 7)) << 4;
    size_t ksrc = (size_t)srow * 128 + schunk;   // + kt*8192 (contiguous tile)
    char* dstK = lds + tid * 16;

    // prologue: stage K buf0 (slot 0 = half0 tile 0, slot 1 = half1 tile h0)
    gload16(Kp + ksrc, dstK);
    if (h0 < nkt) gload16(Kp + (size_t)h0 * 8192 + ksrc, dstK + 8192);

    bf16x8 qf[2];
#pragma unroll
    for (int ks = 0; ks < 2; ++ks)
        qf[ks] = *(const bf16x8*)(Qp + (size_t)q_abs * 64 + ks * 32 + g * 8);

    float l_lane = 0.f;   // per-lane partial; cross-lane reduce ONCE after loop
    f32x4 ot[4] = {};

    for (int r = 0; r < h0; ++r) {
        int buf = r & 1;
        __syncthreads();
        if (r + 1 < h0) {
            int nb2 = (buf ^ 1) * 2;
            gload16(Kp + (size_t)(r + 1) * 8192 + ksrc, dstK + nb2 * 8192);
            int t1n = h0 + r + 1;
            if (t1n < nkt)
                gload16(Kp + (size_t)t1n * 8192 + ksrc, dstK + (nb2 + 1) * 8192);
        }
        int t = half ? h0 + r : r;
        if (t >= nkt) continue;

        const char* kbase = lds + (buf * 2 + half) * 8192;

        // V fragments DIRECT from global (tile-blocked, 8KB L1-resident tile; no swizzle:
        // the k-permutation is baked into the layout, XOR was only an LDS-bank artifact).
        // Issued before QK so latency hides under QK+softmax.
        const char* vgbase = Vp + (size_t)t * 8192;
        bf16x8 vf[8];
#pragma unroll
        for (int hdg = 0; hdg < 4; ++hdg)
#pragma unroll
            for (int mm = 0; mm < 2; ++mm)
                vf[hdg * 2 + mm] = *(const bf16x8*)(
                    vgbase + (hdg * 16 + q) * 128 + (mm * 4 + g) * 16);

        // S' = K_tile @ Q' (Q pre-scaled): lane holds S'[k = kc*16 + g*4 + rr][q]
        f32x4 sacc[4] = {};
#pragma unroll
        for (int kc = 0; kc < 4; ++kc) {
            int row = kc * 16 + q;
#pragma unroll
            for (int ks = 0; ks < 2; ++ks) {
                bf16x8 kf = *(const bf16x8*)(
                    kbase + row * 128 + (((ks * 4 + g) ^ (row & 7)) << 4));
                sacc[kc] = MFMA_16x16x32(kf, qf[ks], sacc[kc]);
            }
        }

        if (t == nkt - 1) {  // diag tile (wave-uniform)
#pragma unroll
            for (int kc = 0; kc < 4; ++kc)
#pragma unroll
                for (int rr = 0; rr < 4; ++rr)
                    if (t * 64 + kc * 16 + g * 4 + rr > q_abs) sacc[kc][rr] = -1e30f;
        }

        // P = exp2(S) via raw v_exp_f32 — no max subtraction (scores bounded)
        float pv[4][4];
#pragma unroll
        for (int kc = 0; kc < 4; ++kc)
#pragma unroll
            for (int rr = 0; rr < 4; ++rr) {
                float p = __builtin_amdgcn_exp2f(sacc[kc][rr]);
                pv[kc][rr] = p;
                l_lane += p;
            }

        bf16x8 pfm[2];
#pragma unroll
        for (int mm = 0; mm < 2; ++mm) {
            union { unsigned u2[4]; bf16x8 v8; } pk;
            pk.u2[0] = cvt_pk_bf16(pv[2 * mm][0], pv[2 * mm][1]);
            pk.u2[1] = cvt_pk_bf16(pv[2 * mm][2], pv[2 * mm][3]);
            pk.u2[2] = cvt_pk_bf16(pv[2 * mm + 1][0], pv[2 * mm + 1][1]);
            pk.u2[3] = cvt_pk_bf16(pv[2 * mm + 1][2], pv[2 * mm + 1][3]);
            pfm[mm] = pk.v8;
        }

        // O^T += V^T @ P over permuted k (V from registers)
#pragma unroll
        for (int hdg = 0; hdg < 4; ++hdg)
#pragma unroll
            for (int mm = 0; mm < 2; ++mm)
                ot[hdg] = MFMA_16x16x32(vf[hdg * 2 + mm], pfm[mm], ot[hdg]);
    }

    // single cross-lane l reduction (sum over g-groups)
    float l_run = l_lane;
    l_run += __shfl_xor(l_run, 16, 64);
    l_run += __shfl_xor(l_run, 32, 64);

    // ---- merge halves via LDS (padded stride 68 -> 2-way banks only); half0 writes Ob --
    __syncthreads();
    float* mO = (float*)lds;                 // [64 q][68 pad] fp32 (17.4 KB <= 32 KB)
    float* mL = (float*)(lds + 64 * 68 * 4); // [64]
    int mrow = ws * 16 + q;
    if (half) {
#pragma unroll
        for (int hdg = 0; hdg < 4; ++hdg)
            *(f32x4*)(mO + mrow * 68 + hdg * 16 + g * 4) = ot[hdg];
        if (g == 0) mL[mrow] = l_run;
    }
    __syncthreads();
    if (!half) {
        float invL = 1.f / (l_run + mL[mrow]);
        int nb = nh >> 3, h = nh & 7;
#pragma unroll
        for (int hdg = 0; hdg < 4; ++hdg) {
            f32x4 o1 = *(const f32x4*)(mO + mrow * 68 + hdg * 16 + g * 4);
            u16x4 wv;
#pragma unroll
            for (int rr = 0; rr < 4; ++rr)
                wv[rr] = f2bf((ot[hdg][rr] + o1[rr]) * invL);
            *(u16x4*)(Ob + ((size_t)(nb * 2048 + q_abs) * 8 + h) * 64 + hdg * 16 + g * 4) =
                wv;
        }
    }
}

extern "C" void kernel_launch(void* const* d_in, const int* in_sizes, int n_in,
                              void* d_out, int out_size, void* d_ws, size_t ws_size,
                              hipStream_t stream) {
    const float* x = (const float*)d_in[0];
    const float* Wq = (const float*)d_in[1];
    const float* bq = (const float*)d_in[2];
    const float* Wk = (const float*)d_in[3];
    const float* bk = (const float*)d_in[4];
    const float* Wv = (const float*)d_in[5];
    const float* bv = (const float*)d_in[6];
    const float* Wo = (const float*)d_in[7];
    const float* bo = (const float*)d_in[8];
    float* out = (float*)d_out;

    char* ws = (char*)d_ws;
    u16* xb = (u16*)ws;                                 // 8 MB; reused as Ob
    u16* Wqkv_t = (u16*)(ws + 8388608);                 // 3 MB
    u16* Wot = (u16*)(ws + 8388608 + 3145728);          // 0.5 MB
    u16* Qb = (u16*)(ws + 8388608 + 3145728 + 524288);  // 3x4 MB contiguous Q,K,Vt
    u16* Kb = Qb + 2097152;
    u16* Vt = Kb + 2097152;
    u16* Ob = xb;                                       // xb dead after QKV GEMM

    pack_all_kernel<<<4544, 256, 0, stream>>>(x, xb, Wq, Wk, Wv, Wqkv_t, Wo, Wot);
    gemm_kernel<1, 64><<<dim3(64, 12), 256, 0, stream>>>(xb, Wqkv_t, 4096, 1536, 1024,
                                                         bq, bk, bv, nullptr, Qb);
    attn_kernel<<<512, 512, 0, stream>>>(Qb, Kb, Vt, Ob);
    gemm_kernel<0, 64><<<dim3(64, 4), 256, 0, stream>>>(Ob, Wot, 4096, 512, 512,
                                                        bo, nullptr, nullptr, out, nullptr);
}

// Round 25
// 58.154 us; speedup vs baseline: 1.3936x; 1.3936x over previous
//
#include <hip/hip_runtime.h>

typedef unsigned short u16;
typedef __attribute__((ext_vector_type(4))) float f32x4;
typedef __attribute__((ext_vector_type(8))) short bf16x8;
typedef __attribute__((ext_vector_type(4))) int i32x4;
typedef __attribute__((ext_vector_type(4))) unsigned short u16x4;

#define MFMA_16x16x32(a, b, c) __builtin_amdgcn_mfma_f32_16x16x32_bf16((a), (b), (c), 0, 0, 0)

typedef __attribute__((address_space(1))) const unsigned int gas_u32;
typedef __attribute__((address_space(3))) unsigned int las_u32;
__device__ __forceinline__ void gload16(const void* g, void* l) {
    __builtin_amdgcn_global_load_lds((gas_u32*)g, (las_u32*)l, 16, 0, 0);
}

__device__ __forceinline__ u16 f2bf(float f) {
    unsigned u = __float_as_uint(f);
    u += 0x7fffu + ((u >> 16) & 1u);
    return (u16)(u >> 16);
}

__device__ __forceinline__ unsigned cvt_pk_bf16(float lo, float hi) {
    unsigned r;
    asm("v_cvt_pk_bf16_f32 %0, %1, %2" : "=v"(r) : "v"(lo), "v"(hi));
    return r;
}

// ---------------- fused pack: x->bf16 | Wqkv permuted+transposed | Wo transposed --------
__global__ void pack_all_kernel(const float* __restrict__ x, u16* __restrict__ xb,
                                const float* __restrict__ Wq, const float* __restrict__ Wk,
                                const float* __restrict__ Wv, u16* __restrict__ Wqkv_t,
                                const float* __restrict__ Wo, u16* __restrict__ Wot) {
    __shared__ u16 tile[64][65];
    int b = blockIdx.x;
    if (b < 4096) {
        int i = b * 256 + threadIdx.x;
        f32x4 v = ((const f32x4*)x)[i];
        u16x4 o;
        o.x = f2bf(v.x); o.y = f2bf(v.y); o.z = f2bf(v.z); o.w = f2bf(v.w);
        ((u16x4*)xb)[i] = o;
        return;
    }
    int tx = threadIdx.x & 63, tq = threadIdx.x >> 6;
    if (b < 4480) {
        int bb = b - 4096;
        int c0 = (bb & 15) * 64;   // K dim (0..1023)
        int j0 = (bb >> 4) * 64;   // N dim (0..1535)
        int tgt = j0 >> 9;
        int jj0 = j0 & 511;
        const float* W = (tgt == 0) ? Wq : (tgt == 1) ? Wk : Wv;
#pragma unroll
        for (int p = 0; p < 16; ++p) {
            int cl = p * 4 + tq;
            int c = c0 + cl;
            int srcRow = 2 * (c & 511) + (c >> 9);
            tile[cl][tx] = f2bf(W[(size_t)srcRow * 512 + jj0 + tx]);
        }
        __syncthreads();
#pragma unroll
        for (int p = 0; p < 16; ++p) {
            int jl = p * 4 + tq;
            Wqkv_t[(size_t)(j0 + jl) * 1024 + c0 + tx] = tile[tx][jl];
        }
    } else {
        int bb = b - 4480;
        int k0 = (bb & 7) * 64;
        int j0 = (bb >> 3) * 64;
#pragma unroll
        for (int p = 0; p < 16; ++p) {
            int kl = p * 4 + tq;
            tile[kl][tx] = f2bf(Wo[(size_t)(k0 + kl) * 512 + j0 + tx]);
        }
        __syncthreads();
#pragma unroll
        for (int p = 0; p < 16; ++p) {
            int jl = p * 4 + tq;
            Wot[(size_t)(j0 + jl) * 512 + k0 + tx] = tile[tx][jl];
        }
    }
}

// ---------------- GEMM: C[M][N] = A[M][K](bf16) @ Bt[N][K](bf16)^T + bias ----------------
// m97-structure, BM=64 grid-uniform (3 blocks/CU for QKV). EPI 1: Q PRE-SCALED by
// 512^-0.5*log2(e); V output TILE-BLOCKED [head][tile][dd][perm(k)].
// Epilogue: bias/indices hoisted; V-fragment r-values consecutive -> u16x4 store.
template <int EPI, int BM>
__global__ __launch_bounds__(256, 2) void gemm_kernel(
    const u16* __restrict__ A, const u16* __restrict__ Bt, int M, int N, int K,
    const float* __restrict__ b0, const float* __restrict__ b1, const float* __restrict__ b2,
    float* __restrict__ outF, u16* __restrict__ outQKV) {
    constexpr int IFR = BM / 32;
    __shared__ __align__(16) char lds[BM * 128 + 16384];
    char* ldsA = lds;
    char* ldsB = lds + BM * 128;
    int t = threadIdx.x;
    int bm = blockIdx.x * BM, bn = blockIdx.y * 128;
    int w = t >> 6, lane = t & 63, g = lane >> 4, q = lane & 15;
    int wr = (w >> 1) * (BM / 2), wc = (w & 1) * 64;
    f32x4 acc[IFR][4] = {};

    int srow = t >> 3;
    int schunk = ((t & 7) ^ (srow & 7)) << 4;
    size_t src_off = (size_t)srow * (size_t)(K * 2) + schunk;
    size_t prow_stride = (size_t)32 * K * 2;
    char* ldsAd = ldsA + t * 16;
    char* ldsBd = ldsB + t * 16;
    const char* Abase = (const char*)A + (size_t)bm * K * 2;
    const char* Bbase = (const char*)Bt + (size_t)bn * K * 2;

    for (int k0 = 0; k0 < K; k0 += 64) {
        __syncthreads();
        const char* Ab = Abase + (size_t)k0 * 2 + src_off;
        const char* Bb = Bbase + (size_t)k0 * 2 + src_off;
#pragma unroll
        for (int p = 0; p < BM / 32; ++p)
            gload16(Ab + p * prow_stride, ldsAd + p * 4096);
#pragma unroll
        for (int p = 0; p < 4; ++p)
            gload16(Bb + p * prow_stride, ldsBd + p * 4096);
        __syncthreads();
#pragma unroll
        for (int ks = 0; ks < 2; ++ks) {
            bf16x8 af[IFR], bfr[4];
#pragma unroll
            for (int i = 0; i < IFR; ++i) {
                int row = wr + i * 16 + q;
                af[i] = *(const bf16x8*)(ldsA + row * 128 + (((ks * 4 + g) ^ (row & 7)) << 4));
            }
#pragma unroll
            for (int j = 0; j < 4; ++j) {
                int col = wc + j * 16 + q;
                bfr[j] = *(const bf16x8*)(ldsB + col * 128 + (((ks * 4 + g) ^ (col & 7)) << 4));
            }
#pragma unroll
            for (int i = 0; i < IFR; ++i)
#pragma unroll
                for (int j = 0; j < 4; ++j)
                    acc[i][j] = MFMA_16x16x32(af[i], bfr[j], acc[i][j]);
        }
    }

#pragma unroll
    for (int i = 0; i < IFR; ++i) {
#pragma unroll
        for (int j = 0; j < 4; ++j) {
            int col = bn + wc + j * 16 + q;
            if (EPI == 0) {
                float bias = b0[col];
#pragma unroll
                for (int r = 0; r < 4; ++r) {
                    int m = bm + wr + i * 16 + g * 4 + r;
                    outF[(size_t)m * N + col] = acc[i][j][r] + bias;
                }
            } else {
                int tt = col >> 9, jj = col & 511;
                const float* bb = (tt == 0) ? b0 : (tt == 1) ? b1 : b2;
                float bias = bb[jj];
                int h = jj >> 6, dd = jj & 63;
                int m0 = bm + wr + i * 16 + g * 4;     // 4-aligned; r-range stays in-tile
                int nb = m0 >> 11, lseq0 = m0 & 2047;
                if (tt == 2) {
                    // t6p for r=0 has low 2 bits 0; dst(r) = dst(0) + r (consecutive u16)
                    int t6 = lseq0 & 63;
                    int t6p = (t6 & 0x20) | ((t6 & 0xC) << 1) | ((t6 & 0x10) >> 2);
                    size_t dst = (size_t)2 * 2097152 +
                                 (size_t)(nb * 8 + h) * 131072 +
                                 (size_t)(lseq0 >> 6) * 4096 + (size_t)dd * 64 + t6p;
                    union { unsigned u2[2]; u16x4 v4; } pk;
                    pk.u2[0] = cvt_pk_bf16(acc[i][j][0] + bias, acc[i][j][1] + bias);
                    pk.u2[1] = cvt_pk_bf16(acc[i][j][2] + bias, acc[i][j][3] + bias);
                    *(u16x4*)(outQKV + dst) = pk.v4;   // 8B-aligned
                } else {
                    float scale = (tt == 0) ? 0.06375872186536607f : 1.0f;
                    size_t base = (size_t)tt * 2097152 +
                                  ((size_t)((nb * 8 + h) * 2048 + lseq0)) * 64 + dd;
#pragma unroll
                    for (int r = 0; r < 4; ++r)
                        outQKV[base + (size_t)r * 64] = f2bf((acc[i][j][r] + bias) * scale);
                }
            }
        }
    }
}

// ------------- flash attention: in-block split-K halves; CU-PAIR balanced mapping ------
// Dispatch fact: XCD = bid%8, blocks sharing a CU are global bids b and b+256.
// hi=bid>>8, u=bid&255: nh=u&15, m=u>>4, qb = hi ? m : 31-m -> CU pair gets {31-m, m}.
// NO-MAX softmax (Q pre-scaled); raw v_exp_f32. l-accumulation uses a f32x4 accumulator
// (4 independent 4-deep add chains/tile instead of one 16-deep serial chain), horizontal
// sum + single shfl_xor pair after the loop. K AND V LDS-staged (global-V loses: R15/R24).
__global__ __launch_bounds__(512, 4) void attn_kernel(
    const u16* __restrict__ Qb, const u16* __restrict__ Kb, const u16* __restrict__ Vt,
    u16* __restrict__ Ob) {
    __shared__ __align__(16) char lds[65536];  // K[2buf][2half][8KB] | V at +32KB
    int bid = blockIdx.x;
    int hi = bid >> 8;                 // 0 or 1
    int u = bid & 255;
    int nh = u & 15;
    int m = u >> 4;                    // [0,16)
    int qb = hi ? m : 31 - m;          // CU-pair (b, b+256): {31-m, m}
    int tid = threadIdx.x;
    int w = tid >> 6, lane = tid & 63;
    int g = lane >> 4, q = lane & 15;
    int half = w >> 2, ws = w & 3;
    int qt = qb * 4 + ws;
    int q_abs = qt * 16 + q;
    int nkt = qb + 1;
    int h0 = (nkt + 1) >> 1;

    const u16* Qp = Qb + (size_t)nh * 131072;
    const char* Kp = (const char*)(Kb + (size_t)nh * 131072);
    const char* Vp = (const char*)(Vt + (size_t)nh * 131072);

    int srow = tid >> 3;
    int schunk = ((tid & 7) ^ (srow & 7)) << 4;
    size_t ksrc = (size_t)srow * 128 + schunk;   // + kt*8192 (contiguous tile)
    size_t vsrc = (size_t)srow * 128 + schunk;   // + kt*8192 (tile-blocked V)
    char* dstK = lds + tid * 16;
    char* dstV = lds + 32768 + tid * 16;

    // prologue: stage buf0 (slot 0 = half0 tile 0, slot 1 = half1 tile h0)
    gload16(Kp + ksrc, dstK);
    gload16(Vp + vsrc, dstV);
    if (h0 < nkt) {
        gload16(Kp + (size_t)h0 * 8192 + ksrc, dstK + 8192);
        gload16(Vp + (size_t)h0 * 8192 + vsrc, dstV + 8192);
    }

    bf16x8 qf[2];
#pragma unroll
    for (int ks = 0; ks < 2; ++ks)
        qf[ks] = *(const bf16x8*)(Qp + (size_t)q_abs * 64 + ks * 32 + g * 8);

    f32x4 lacc = {};      // 4 independent accumulation chains
    f32x4 ot[4] = {};

    for (int r = 0; r < h0; ++r) {
        int buf = r & 1;
        __syncthreads();
        if (r + 1 < h0) {
            int nb2 = (buf ^ 1) * 2;
            gload16(Kp + (size_t)(r + 1) * 8192 + ksrc, dstK + nb2 * 8192);
            gload16(Vp + (size_t)(r + 1) * 8192 + vsrc, dstV + nb2 * 8192);
            int t1n = h0 + r + 1;
            if (t1n < nkt) {
                gload16(Kp + (size_t)t1n * 8192 + ksrc, dstK + (nb2 + 1) * 8192);
                gload16(Vp + (size_t)t1n * 8192 + vsrc, dstV + (nb2 + 1) * 8192);
            }
        }
        int t = half ? h0 + r : r;
        if (t >= nkt) continue;

        const char* kbase = lds + (buf * 2 + half) * 8192;
        const char* vbase = lds + 32768 + (buf * 2 + half) * 8192;

        // S' = K_tile @ Q' (Q pre-scaled): lane holds S'[k = kc*16 + g*4 + rr][q]
        f32x4 sacc[4] = {};
#pragma unroll
        for (int kc = 0; kc < 4; ++kc) {
            int row = kc * 16 + q;
#pragma unroll
            for (int ks = 0; ks < 2; ++ks) {
                bf16x8 kf = *(const bf16x8*)(
                    kbase + row * 128 + (((ks * 4 + g) ^ (row & 7)) << 4));
                sacc[kc] = MFMA_16x16x32(kf, qf[ks], sacc[kc]);
            }
        }

        if (t == nkt - 1) {  // diag tile (wave-uniform)
#pragma unroll
            for (int kc = 0; kc < 4; ++kc)
#pragma unroll
                for (int rr = 0; rr < 4; ++rr)
                    if (t * 64 + kc * 16 + g * 4 + rr > q_abs) sacc[kc][rr] = -1e30f;
        }

        // P = exp2(S) via raw v_exp_f32 — no max subtraction (scores bounded)
        float pv[4][4];
#pragma unroll
        for (int kc = 0; kc < 4; ++kc)
#pragma unroll
            for (int rr = 0; rr < 4; ++rr) {
                float p = __builtin_amdgcn_exp2f(sacc[kc][rr]);
                pv[kc][rr] = p;
                lacc[rr] += p;
            }

        bf16x8 pfm[2];
#pragma unroll
        for (int mm = 0; mm < 2; ++mm) {
            union { unsigned u2[4]; bf16x8 v8; } pk;
            pk.u2[0] = cvt_pk_bf16(pv[2 * mm][0], pv[2 * mm][1]);
            pk.u2[1] = cvt_pk_bf16(pv[2 * mm][2], pv[2 * mm][3]);
            pk.u2[2] = cvt_pk_bf16(pv[2 * mm + 1][0], pv[2 * mm + 1][1]);
            pk.u2[3] = cvt_pk_bf16(pv[2 * mm + 1][2], pv[2 * mm + 1][3]);
            pfm[mm] = pk.v8;
        }

        // O^T += V^T @ P over permuted k
#pragma unroll
        for (int hdg = 0; hdg < 4; ++hdg) {
            int row = hdg * 16 + q;
#pragma unroll
            for (int mm = 0; mm < 2; ++mm) {
                bf16x8 vfrag = *(const bf16x8*)(
                    vbase + row * 128 + (((mm * 4 + g) ^ (row & 7)) << 4));
                ot[hdg] = MFMA_16x16x32(vfrag, pfm[mm], ot[hdg]);
            }
        }
    }

    // horizontal + cross-lane l reduction (once)
    float l_run = (lacc[0] + lacc[1]) + (lacc[2] + lacc[3]);
    l_run += __shfl_xor(l_run, 16, 64);
    l_run += __shfl_xor(l_run, 32, 64);

    // ---- merge halves via LDS (padded stride 68 -> 2-way banks only); half0 writes Ob --
    __syncthreads();
    float* mO = (float*)lds;                 // [64 q][68 pad] fp32
    float* mL = (float*)(lds + 64 * 68 * 4); // [64]
    int mrow = ws * 16 + q;
    if (half) {
#pragma unroll
        for (int hdg = 0; hdg < 4; ++hdg)
            *(f32x4*)(mO + mrow * 68 + hdg * 16 + g * 4) = ot[hdg];
        if (g == 0) mL[mrow] = l_run;
    }
    __syncthreads();
    if (!half) {
        float invL = 1.f / (l_run + mL[mrow]);
        int nb = nh >> 3, h = nh & 7;
#pragma unroll
        for (int hdg = 0; hdg < 4; ++hdg) {
            f32x4 o1 = *(const f32x4*)(mO + mrow * 68 + hdg * 16 + g * 4);
            u16x4 wv;
#pragma unroll
            for (int rr = 0; rr < 4; ++rr)
                wv[rr] = f2bf((ot[hdg][rr] + o1[rr]) * invL);
            *(u16x4*)(Ob + ((size_t)(nb * 2048 + q_abs) * 8 + h) * 64 + hdg * 16 + g * 4) =
                wv;
        }
    }
}

extern "C" void kernel_launch(void* const* d_in, const int* in_sizes, int n_in,
                              void* d_out, int out_size, void* d_ws, size_t ws_size,
                              hipStream_t stream) {
    const float* x = (const float*)d_in[0];
    const float* Wq = (const float*)d_in[1];
    const float* bq = (const float*)d_in[2];
    const float* Wk = (const float*)d_in[3];
    const float* bk = (const float*)d_in[4];
    const float* Wv = (const float*)d_in[5];
    const float* bv = (const float*)d_in[6];
    const float* Wo = (const float*)d_in[7];
    const float* bo = (const float*)d_in[8];
    float* out = (float*)d_out;

    char* ws = (char*)d_ws;
    u16* xb = (u16*)ws;                                 // 8 MB; reused as Ob
    u16* Wqkv_t = (u16*)(ws + 8388608);                 // 3 MB
    u16* Wot = (u16*)(ws + 8388608 + 3145728);          // 0.5 MB
    u16* Qb = (u16*)(ws + 8388608 + 3145728 + 524288);  // 3x4 MB contiguous Q,K,Vt
    u16* Kb = Qb + 2097152;
    u16* Vt = Kb + 2097152;
    u16* Ob = xb;                                       // xb dead after QKV GEMM

    pack_all_kernel<<<4544, 256, 0, stream>>>(x, xb, Wq, Wk, Wv, Wqkv_t, Wo, Wot);
    gemm_kernel<1, 64><<<dim3(64, 12), 256, 0, stream>>>(xb, Wqkv_t, 4096, 1536, 1024,
                                                         bq, bk, bv, nullptr, Qb);
    attn_kernel<<<512, 512, 0, stream>>>(Qb, Kb, Vt, Ob);
    gemm_kernel<0, 64><<<dim3(64, 4), 256, 0, stream>>>(Ob, Wot, 4096, 512, 512,
                                                        bo, nullptr, nullptr, out, nullptr);
}